// Round 6
// baseline (215.377 us; speedup 1.0000x reference)
//
#include <hip/hip_runtime.h>
#include <hip/hip_bf16.h>

// Problem constants
#define B_    2
#define S_    2048
#define E_    1024
#define H_    16
#define HD_   64
#define M_    (B_ * S_)     // 4096 rows of x
#define QKVN  (3 * E_)      // 3072

typedef __attribute__((ext_vector_type(8))) short  short8;
typedef __attribute__((ext_vector_type(4))) float  f32x4;
typedef __attribute__((ext_vector_type(4))) unsigned short us16x4;

static __device__ __forceinline__ unsigned short f2bf(float f) {
  union { float f; unsigned int u; } c; c.f = f;
  unsigned int u = c.u;
  return (unsigned short)((u + 0x7fffu + ((u >> 16) & 1u)) >> 16);  // RNE
}

// async global->LDS, 16B per lane; LDS dest must be wave-uniform base (+lane*16)
static __device__ __forceinline__ void gload16(unsigned short* lds,
                                               const unsigned short* g) {
  __builtin_amdgcn_global_load_lds(
      (__attribute__((address_space(1))) void*)g,
      (__attribute__((address_space(3))) void*)lds, 16, 0, 0);
}

// ---------------------------------------------------------------------------
// fp32 -> bf16 convert (vectorized, 4 elems/thread)
// ---------------------------------------------------------------------------
__global__ __launch_bounds__(256) void cvt_f32_to_bf16(
    const float* __restrict__ in, unsigned short* __restrict__ out, int n4) {
  int i = blockIdx.x * 256 + threadIdx.x;
  if (i < n4) {
    float4 v = reinterpret_cast<const float4*>(in)[i];
    ushort4 r;
    r.x = f2bf(v.x); r.y = f2bf(v.y); r.z = f2bf(v.z); r.w = f2bf(v.w);
    reinterpret_cast<ushort4*>(out)[i] = r;
  }
}

// ---------------------------------------------------------------------------
// Generic C[M,N] = A(MxK,rm) * Bt(NxK,rm)^T. Tile 128 x BN, 4 waves (2x2).
// BN=128: wave 64x64 (4x4 frags). BN=64: wave 64x32 (4x2 frags).
// BF16_OUT=1: bf16 store; 0: fp32 + bias.
// ---------------------------------------------------------------------------
template <int BF16_OUT, int BN>
__global__ __launch_bounds__(256) void gemm_bt(
    const unsigned short* __restrict__ A, const unsigned short* __restrict__ Bt,
    void* __restrict__ Cout, const float* __restrict__ bias,
    int M, int N, int K, int ldc) {
  constexpr int NF = BN / 32;  // B-frags per wave
  __shared__ alignas(16) unsigned short lds_a[128 * 64];
  __shared__ alignas(16) unsigned short lds_b[BN * 64];
  const int t  = threadIdx.x;
  const int w  = t >> 6, l = t & 63, g = l >> 4, lr = l & 15;
  const int bm = blockIdx.y * 128, bn = blockIdx.x * BN;
  const int wr = (w >> 1) * 64,  wc = (w & 1) * (BN / 2);

  f32x4 acc[4][NF] = {};

  for (int k0 = 0; k0 < K; k0 += 64) {
    __syncthreads();
#pragma unroll
    for (int i = 0; i < 4; i++) {
      const int pass = w * 4 + i;            // 0..15 (wave-uniform)
      const int r = pass * 8 + (l >> 3);     // 0..127
      const int c = (l & 7) ^ (r & 7);       // pre-swizzled source chunk
      gload16(lds_a + pass * 512, A + (size_t)(bm + r) * K + k0 + c * 8);
    }
#pragma unroll
    for (int i = 0; i < NF; i++) {
      const int pass = w * NF + i;           // 0..4*NF-1 (wave-uniform)
      const int r = pass * 8 + (l >> 3);     // 0..BN-1
      const int c = (l & 7) ^ (r & 7);
      gload16(lds_b + pass * 512, Bt + (size_t)(bn + r) * K + k0 + c * 8);
    }
    __syncthreads();

    short8 af[4][2], bfr[NF][2];
#pragma unroll
    for (int m = 0; m < 4; m++) {
      const int R = wr + m * 16 + lr;
#pragma unroll
      for (int kk = 0; kk < 2; kk++)
        af[m][kk] = *(const short8*)((const char*)lds_a +
            ((R * 128 + kk * 64 + g * 16) ^ ((R & 7) << 4)));
    }
#pragma unroll
    for (int n = 0; n < NF; n++) {
      const int R = wc + n * 16 + lr;
#pragma unroll
      for (int kk = 0; kk < 2; kk++)
        bfr[n][kk] = *(const short8*)((const char*)lds_b +
            ((R * 128 + kk * 64 + g * 16) ^ ((R & 7) << 4)));
    }
#pragma unroll
    for (int m = 0; m < 4; m++)
#pragma unroll
      for (int n = 0; n < NF; n++) {
        acc[m][n] = __builtin_amdgcn_mfma_f32_16x16x32_bf16(
            af[m][0], bfr[n][0], acc[m][n], 0, 0, 0);
        acc[m][n] = __builtin_amdgcn_mfma_f32_16x16x32_bf16(
            af[m][1], bfr[n][1], acc[m][n], 0, 0, 0);
      }
  }

#pragma unroll
  for (int m = 0; m < 4; m++)
#pragma unroll
    for (int n = 0; n < NF; n++)
#pragma unroll
      for (int j = 0; j < 4; j++) {
        const int row = bm + wr + m * 16 + g * 4 + j;
        const int col = bn + wc + n * 16 + lr;
        const float v = acc[m][n][j];
        if constexpr (BF16_OUT) {
          ((unsigned short*)Cout)[(size_t)row * ldc + col] = f2bf(v);
        } else {
          ((float*)Cout)[(size_t)row * ldc + col] = v + bias[col];
        }
      }
}

// ---------------------------------------------------------------------------
// QKV GEMM with split epilogue: cols are h*192 + cls*64 + d (cls 0=Q,1=K,2=V).
//   Q -> q_bf (B,S,E) head-major d; K -> k_bf (B,S,E); V -> vt_bf (B,H,64,S)
// Each 16-col fragment is class-uniform (16 | 64 | 192). V^T store: the C/D
// fragment's 4 consecutive rows (j) become 4 consecutive s -> one 8B store.
// ---------------------------------------------------------------------------
__global__ __launch_bounds__(256) void gemm_qkv(
    const unsigned short* __restrict__ A, const unsigned short* __restrict__ Bt,
    unsigned short* __restrict__ q_bf, unsigned short* __restrict__ k_bf,
    unsigned short* __restrict__ vt_bf, int K) {
  __shared__ alignas(16) unsigned short lds_a[128 * 64];
  __shared__ alignas(16) unsigned short lds_b[128 * 64];
  const int t  = threadIdx.x;
  const int w  = t >> 6, l = t & 63, g = l >> 4, lr = l & 15;
  const int bm = blockIdx.y * 128, bn = blockIdx.x * 128;
  const int wr = (w >> 1) * 64,  wc = (w & 1) * 64;

  f32x4 acc[4][4] = {};

  for (int k0 = 0; k0 < K; k0 += 64) {
    __syncthreads();
#pragma unroll
    for (int i = 0; i < 4; i++) {
      const int pass = w * 4 + i;
      const int r = pass * 8 + (l >> 3);
      const int c = (l & 7) ^ (r & 7);
      gload16(lds_a + pass * 512, A + (size_t)(bm + r) * K + k0 + c * 8);
      gload16(lds_b + pass * 512, Bt + (size_t)(bn + r) * K + k0 + c * 8);
    }
    __syncthreads();

    short8 af[4][2], bfr[4][2];
#pragma unroll
    for (int m = 0; m < 4; m++) {
      const int R = wr + m * 16 + lr;
#pragma unroll
      for (int kk = 0; kk < 2; kk++)
        af[m][kk] = *(const short8*)((const char*)lds_a +
            ((R * 128 + kk * 64 + g * 16) ^ ((R & 7) << 4)));
    }
#pragma unroll
    for (int n = 0; n < 4; n++) {
      const int R = wc + n * 16 + lr;
#pragma unroll
      for (int kk = 0; kk < 2; kk++)
        bfr[n][kk] = *(const short8*)((const char*)lds_b +
            ((R * 128 + kk * 64 + g * 16) ^ ((R & 7) << 4)));
    }
#pragma unroll
    for (int m = 0; m < 4; m++)
#pragma unroll
      for (int n = 0; n < 4; n++) {
        acc[m][n] = __builtin_amdgcn_mfma_f32_16x16x32_bf16(
            af[m][0], bfr[n][0], acc[m][n], 0, 0, 0);
        acc[m][n] = __builtin_amdgcn_mfma_f32_16x16x32_bf16(
            af[m][1], bfr[n][1], acc[m][n], 0, 0, 0);
      }
  }

  const int b = bm >> 11;  // 128-row tiles never cross the S=2048 boundary
#pragma unroll
  for (int n = 0; n < 4; n++) {
    const int col0  = bn + wc + n * 16;       // fragment class is uniform
    const int hcls  = col0 / 192;
    const int cls   = (col0 % 192) / 64;      // 0=Q, 1=K, 2=V
    const int cbase = col0 & 63;
    if (cls == 2) {
      const int d  = cbase + lr;
      const int sl = (bm & 2047) + wr + g * 4;  // + m*16 below
#pragma unroll
      for (int m = 0; m < 4; m++) {
        us16x4 pk;
#pragma unroll
        for (int j = 0; j < 4; j++) pk[j] = f2bf(acc[m][n][j]);
        *(us16x4*)(vt_bf +
            ((size_t)((b * H_ + hcls) * 64 + d) * S_ + sl + m * 16)) = pk;
      }
    } else {
      unsigned short* dst = (cls == 0) ? q_bf : k_bf;
      const int col = hcls * 64 + cbase + lr;
#pragma unroll
      for (int m = 0; m < 4; m++)
#pragma unroll
        for (int j = 0; j < 4; j++) {
          const int row = bm + wr + m * 16 + g * 4 + j;
          dst[(size_t)row * E_ + col] = f2bf(acc[m][n][j]);
        }
    }
  }
}

// ---------------------------------------------------------------------------
// Causal flash attention, swapped-operand form (lane-local softmax).
// Sources: q_bf/k_bf (B,S,E) head-major, vt_bf (B,H,64,S) pre-transposed V.
// V^T stages exactly like K (ds_write_b128, (row&7)<<4 XOR swizzle); PV
// A-frag read is the same pattern as the QK K-frag read. Rest unchanged
// from round 5 (known-good).
// ---------------------------------------------------------------------------
__global__ __launch_bounds__(256) void attn_fwd(
    const unsigned short* __restrict__ q_bf,
    const unsigned short* __restrict__ k_bf,
    const unsigned short* __restrict__ vt_bf,
    unsigned short* __restrict__ attn_out) {
  __shared__ alignas(16) unsigned short lds_k[64 * 64];     // 8 KB  [kv][d]
  __shared__ alignas(16) unsigned short lds_vt[64 * 64];    // 8 KB  [d][kv]
  __shared__ alignas(16) unsigned short lds_p[4][32 * 64];  // 16 KB per-wave P

  const int t = threadIdx.x;
  const int w = t >> 6, l = t & 63, g = (l >> 4) & 3, lr = l & 15;
  const int bid = blockIdx.x;
  const int bh = bid & 31, b = bh >> 4, h = bh & 15;
  const int rr = bid >> 5;                       // 0..15
  const int bx = (rr < 8) ? rr : 23 - rr;        // pair light+heavy per CU
  const int q0 = bx * 128;
  const int qw = q0 + w * 32;
  const unsigned short* qbase = q_bf + (size_t)b * S_ * E_ + h * HD_;
  const unsigned short* kbase = k_bf + (size_t)b * S_ * E_ + h * HD_;
  const unsigned short* vbase = vt_bf + (size_t)(b * H_ + h) * 64 * S_;

  // Q fragments (B-side): lane (g,lr): Q[qw+m*16+lr][g*8 + kk*32 + 0..7]
  short8 qf[2][2];
#pragma unroll
  for (int m = 0; m < 2; m++) {
    const unsigned short* qp = qbase + (size_t)(qw + m * 16 + lr) * E_ + g * 8;
    qf[m][0] = *(const short8*)qp;
    qf[m][1] = *(const short8*)(qp + 32);
  }

  // O^T accumulator: o[m][dt][j] = O[q=qw+m*16+lr][d=dt*16+g*4+j]
  f32x4 o[2][4] = {};
  float m_r[2] = {-3.0e38f, -3.0e38f};
  float l_r[2] = {0.f, 0.f};
  const float SCALE2 = 0.18033688011112042f;  // 0.125 * log2(e)

  const int numt = 2 * bx + 2;
  const int r_st = t >> 3;      // 0..31 staging row base
  const int kc   = t & 7;       // staging 16B column chunk

  // prologue: load KV tile 0 into regs
  short8 kreg[2], vreg[2];
#pragma unroll
  for (int p = 0; p < 2; p++) {
    const int r = p * 32 + r_st;
    kreg[p] = *(const short8*)(kbase + (size_t)r * E_ + kc * 8);
    vreg[p] = *(const short8*)(vbase + (size_t)r * S_ + kc * 8);
  }

  for (int kt = 0; kt < numt; kt++) {
    const int k0 = kt * 64;
    // ---- regs -> LDS (K and V^T identical pattern) ----
#pragma unroll
    for (int p = 0; p < 2; p++) {
      const int r = p * 32 + r_st;
      const int off = (r * 128 + kc * 16) ^ ((r & 7) << 4);
      *(short8*)((char*)lds_k + off)  = kreg[p];
      *(short8*)((char*)lds_vt + off) = vreg[p];
    }
    // ---- prefetch KV tile kt+1 into regs ----
    if (kt + 1 < numt) {
#pragma unroll
      for (int p = 0; p < 2; p++) {
        const int r = p * 32 + r_st;
        kreg[p] = *(const short8*)(kbase + (size_t)(k0 + 64 + r) * E_ + kc * 8);
        vreg[p] = *(const short8*)(vbase + (size_t)r * S_ + k0 + 64 + kc * 8);
      }
    }
    __syncthreads();

    if (k0 <= qw + 31) {  // wave-uniform causal gate
      // ---- S^T[64 kv][32 q] = K·Q^T (swapped operands) ----
      f32x4 st[2][4];
      __builtin_amdgcn_s_setprio(1);
#pragma unroll
      for (int n = 0; n < 4; n++) {
        const int R = n * 16 + lr;
        const int sw = (R & 7) << 4;
        short8 kf0 = *(const short8*)((const char*)lds_k +
            ((R * 128 + g * 16) ^ sw));
        short8 kf1 = *(const short8*)((const char*)lds_k +
            ((R * 128 + 64 + g * 16) ^ sw));
#pragma unroll
        for (int m = 0; m < 2; m++) {
          f32x4 z = {};
          z = __builtin_amdgcn_mfma_f32_16x16x32_bf16(kf0, qf[m][0], z, 0, 0, 0);
          z = __builtin_amdgcn_mfma_f32_16x16x32_bf16(kf1, qf[m][1], z, 0, 0, 0);
          st[m][n] = z;
        }
      }
      __builtin_amdgcn_s_setprio(0);

      const bool diag = (k0 + 63 > qw);

      // ---- lane-local softmax (q = qw+m*16+lr) + packed P writes ----
#pragma unroll
      for (int m = 0; m < 2; m++) {
        const int qrow = qw + m * 16 + lr;
        if (diag) {
#pragma unroll
          for (int n = 0; n < 4; n++)
#pragma unroll
            for (int j = 0; j < 4; j++)
              if ((k0 + n * 16 + g * 4 + j) > qrow) st[m][n][j] = -3.0e38f;
        }
        float mx = st[m][0][0];
#pragma unroll
        for (int n = 0; n < 4; n++)
#pragma unroll
          for (int j = 0; j < 4; j++) mx = fmaxf(mx, st[m][n][j]);
        mx = fmaxf(mx, __shfl_xor(mx, 16, 64));
        mx = fmaxf(mx, __shfl_xor(mx, 32, 64));
        const float mn = fmaxf(m_r[m], mx * SCALE2);
        const float c  = exp2f(m_r[m] - mn);
        m_r[m] = mn;
        float p[4][4];
        float sum = 0.f;
#pragma unroll
        for (int n = 0; n < 4; n++)
#pragma unroll
          for (int j = 0; j < 4; j++) {
            p[n][j] = exp2f(fmaf(st[m][n][j], SCALE2, -mn));
            sum += p[n][j];
          }
        sum += __shfl_xor(sum, 16, 64);
        sum += __shfl_xor(sum, 32, 64);
        l_r[m] = l_r[m] * c + sum;
#pragma unroll
        for (int dt = 0; dt < 4; dt++) o[m][dt] *= c;
        char* pb = (char*)lds_p[w];
        const int rowb = (m * 16 + lr) * 128;
        const int sw   = (lr & 7) << 4;
#pragma unroll
        for (int n = 0; n < 4; n++) {
          unsigned w0, w1;
          __asm__("v_cvt_pk_bf16_f32 %0, %1, %2"
                  : "=v"(w0) : "v"(p[n][0]), "v"(p[n][1]));
          __asm__("v_cvt_pk_bf16_f32 %0, %1, %2"
                  : "=v"(w1) : "v"(p[n][2]), "v"(p[n][3]));
          uint2 val; val.x = w0; val.y = w1;
          *(uint2*)(pb + ((rowb + n * 32 + g * 8) ^ sw)) = val;
        }
      }
      __asm__ volatile("s_waitcnt lgkmcnt(0)" ::: "memory");

      // ---- PV: O^T += V^T(64d x 64kv) · P^T(64kv x 32q) ----
      short8 pf[2][2];
#pragma unroll
      for (int m = 0; m < 2; m++) {
        const int rowb = (m * 16 + lr) * 128;
        const int sw   = (lr & 7) << 4;
        pf[m][0] = *(const short8*)((const char*)lds_p[w] +
            ((rowb + g * 16) ^ sw));
        pf[m][1] = *(const short8*)((const char*)lds_p[w] +
            ((rowb + 64 + g * 16) ^ sw));
      }
      __builtin_amdgcn_s_setprio(1);
#pragma unroll
      for (int dt = 0; dt < 4; dt++) {
        const int R = dt * 16 + lr;
        const int sw = (R & 7) << 4;
        short8 vf0 = *(const short8*)((const char*)lds_vt +
            ((R * 128 + g * 16) ^ sw));
        short8 vf1 = *(const short8*)((const char*)lds_vt +
            ((R * 128 + 64 + g * 16) ^ sw));
#pragma unroll
        for (int m = 0; m < 2; m++) {
          o[m][dt] = __builtin_amdgcn_mfma_f32_16x16x32_bf16(
              vf0, pf[m][0], o[m][dt], 0, 0, 0);
          o[m][dt] = __builtin_amdgcn_mfma_f32_16x16x32_bf16(
              vf1, pf[m][1], o[m][dt], 0, 0, 0);
        }
      }
      __builtin_amdgcn_s_setprio(0);
    }

    __syncthreads();
  }

  // ---- epilogue: O = O^T scaled by lane-local 1/l, 8B stores ----
  unsigned short* outp = attn_out + (size_t)b * S_ * E_ + h * HD_;
#pragma unroll
  for (int m = 0; m < 2; m++) {
    const float inv = 1.0f / l_r[m];
    const int qrow = qw + m * 16 + lr;
#pragma unroll
    for (int dt = 0; dt < 4; dt++) {
      us16x4 w4;
#pragma unroll
      for (int j = 0; j < 4; j++) w4[j] = f2bf(o[m][dt][j] * inv);
      *(us16x4*)(outp + (size_t)qrow * E_ + dt * 16 + g * 4) = w4;
    }
  }
}

// ---------------------------------------------------------------------------
extern "C" void kernel_launch(void* const* d_in, const int* in_sizes, int n_in,
                              void* d_out, int out_size, void* d_ws, size_t ws_size,
                              hipStream_t stream) {
  (void)in_sizes; (void)n_in; (void)out_size; (void)ws_size;
  const float* x      = (const float*)d_in[0];
  const float* w_qkv  = (const float*)d_in[1];
  const float* w_proj = (const float*)d_in[2];
  const float* b_proj = (const float*)d_in[3];
  float* out = (float*)d_out;

  // workspace layout (all bf16):
  unsigned short* x_bf     = (unsigned short*)d_ws;                 // 4096x1024
  unsigned short* wqkv_bf  = x_bf    + (size_t)M_ * E_;             // 3072x1024
  unsigned short* wproj_bf = wqkv_bf + (size_t)QKVN * E_;           // 1024x1024
  unsigned short* q_bf     = wproj_bf + (size_t)E_ * E_;            // 4096x1024
  unsigned short* k_bf     = q_bf    + (size_t)M_ * E_;             // 4096x1024
  unsigned short* vt_bf    = k_bf    + (size_t)M_ * E_;             // (B,H,64,S)
  unsigned short* attn_bf  = vt_bf   + (size_t)M_ * E_;             // 4096x1024

  int n4;
  n4 = M_ * E_ / 4;
  cvt_f32_to_bf16<<<(n4 + 255) / 256, 256, 0, stream>>>(x, x_bf, n4);
  n4 = QKVN * E_ / 4;
  cvt_f32_to_bf16<<<(n4 + 255) / 256, 256, 0, stream>>>(w_qkv, wqkv_bf, n4);
  n4 = E_ * E_ / 4;
  cvt_f32_to_bf16<<<(n4 + 255) / 256, 256, 0, stream>>>(w_proj, wproj_bf, n4);

  // QKV projection with split Q/K/V^T epilogue
  gemm_qkv<<<dim3(QKVN / 128, M_ / 128), 256, 0, stream>>>(
      x_bf, wqkv_bf, q_bf, k_bf, vt_bf, E_);

  // causal attention: 512 blocks, work-paired
  attn_fwd<<<dim3(512), 256, 0, stream>>>(q_bf, k_bf, vt_bf, attn_bf);

  // output projection + bias: BN=64 tile -> 512 blocks (2/CU)
  gemm_bt<0, 64><<<dim3(E_ / 64, M_ / 128), 256, 0, stream>>>(
      attn_bf, wproj_bf, (void*)out, b_proj, M_, E_, E_, E_);
}

// Round 7
// 209.018 us; speedup vs baseline: 1.0304x; 1.0304x over previous
//
#include <hip/hip_runtime.h>
#include <hip/hip_bf16.h>

// Problem constants
#define B_    2
#define S_    2048
#define E_    1024
#define H_    16
#define HD_   64
#define M_    (B_ * S_)     // 4096 rows of x
#define QKVN  (3 * E_)      // 3072

typedef __attribute__((ext_vector_type(8))) short  short8;
typedef __attribute__((ext_vector_type(4))) float  f32x4;
typedef __attribute__((ext_vector_type(4))) unsigned short us16x4;

static __device__ __forceinline__ unsigned short f2bf(float f) {
  union { float f; unsigned int u; } c; c.f = f;
  unsigned int u = c.u;
  return (unsigned short)((u + 0x7fffu + ((u >> 16) & 1u)) >> 16);  // RNE
}

// async global->LDS, 16B per lane; LDS dest must be wave-uniform base (+lane*16)
static __device__ __forceinline__ void gload16(unsigned short* lds,
                                               const unsigned short* g) {
  __builtin_amdgcn_global_load_lds(
      (__attribute__((address_space(1))) void*)g,
      (__attribute__((address_space(3))) void*)lds, 16, 0, 0);
}

// ---------------------------------------------------------------------------
// fp32 -> bf16 convert (vectorized, 4 elems/thread)
// ---------------------------------------------------------------------------
__global__ __launch_bounds__(256) void cvt_f32_to_bf16(
    const float* __restrict__ in, unsigned short* __restrict__ out, int n4) {
  int i = blockIdx.x * 256 + threadIdx.x;
  if (i < n4) {
    float4 v = reinterpret_cast<const float4*>(in)[i];
    ushort4 r;
    r.x = f2bf(v.x); r.y = f2bf(v.y); r.z = f2bf(v.z); r.w = f2bf(v.w);
    reinterpret_cast<ushort4*>(out)[i] = r;
  }
}

// ---------------------------------------------------------------------------
// Generic C[M,N] = A(MxK,rm) * Bt(NxK,rm)^T. Tile 128 x BN, 4 waves (2x2).
// (unchanged, known-good)
// ---------------------------------------------------------------------------
template <int BF16_OUT, int BN>
__global__ __launch_bounds__(256) void gemm_bt(
    const unsigned short* __restrict__ A, const unsigned short* __restrict__ Bt,
    void* __restrict__ Cout, const float* __restrict__ bias,
    int M, int N, int K, int ldc) {
  constexpr int NF = BN / 32;  // B-frags per wave
  __shared__ alignas(16) unsigned short lds_a[128 * 64];
  __shared__ alignas(16) unsigned short lds_b[BN * 64];
  const int t  = threadIdx.x;
  const int w  = t >> 6, l = t & 63, g = l >> 4, lr = l & 15;
  const int bm = blockIdx.y * 128, bn = blockIdx.x * BN;
  const int wr = (w >> 1) * 64,  wc = (w & 1) * (BN / 2);

  f32x4 acc[4][NF] = {};

  for (int k0 = 0; k0 < K; k0 += 64) {
    __syncthreads();
#pragma unroll
    for (int i = 0; i < 4; i++) {
      const int pass = w * 4 + i;            // 0..15 (wave-uniform)
      const int r = pass * 8 + (l >> 3);     // 0..127
      const int c = (l & 7) ^ (r & 7);       // pre-swizzled source chunk
      gload16(lds_a + pass * 512, A + (size_t)(bm + r) * K + k0 + c * 8);
    }
#pragma unroll
    for (int i = 0; i < NF; i++) {
      const int pass = w * NF + i;           // 0..4*NF-1 (wave-uniform)
      const int r = pass * 8 + (l >> 3);     // 0..BN-1
      const int c = (l & 7) ^ (r & 7);
      gload16(lds_b + pass * 512, Bt + (size_t)(bn + r) * K + k0 + c * 8);
    }
    __syncthreads();

    short8 af[4][2], bfr[NF][2];
#pragma unroll
    for (int m = 0; m < 4; m++) {
      const int R = wr + m * 16 + lr;
#pragma unroll
      for (int kk = 0; kk < 2; kk++)
        af[m][kk] = *(const short8*)((const char*)lds_a +
            ((R * 128 + kk * 64 + g * 16) ^ ((R & 7) << 4)));
    }
#pragma unroll
    for (int n = 0; n < NF; n++) {
      const int R = wc + n * 16 + lr;
#pragma unroll
      for (int kk = 0; kk < 2; kk++)
        bfr[n][kk] = *(const short8*)((const char*)lds_b +
            ((R * 128 + kk * 64 + g * 16) ^ ((R & 7) << 4)));
    }
#pragma unroll
    for (int m = 0; m < 4; m++)
#pragma unroll
      for (int n = 0; n < NF; n++) {
        acc[m][n] = __builtin_amdgcn_mfma_f32_16x16x32_bf16(
            af[m][0], bfr[n][0], acc[m][n], 0, 0, 0);
        acc[m][n] = __builtin_amdgcn_mfma_f32_16x16x32_bf16(
            af[m][1], bfr[n][1], acc[m][n], 0, 0, 0);
      }
  }

#pragma unroll
  for (int m = 0; m < 4; m++)
#pragma unroll
    for (int n = 0; n < NF; n++)
#pragma unroll
      for (int j = 0; j < 4; j++) {
        const int row = bm + wr + m * 16 + g * 4 + j;
        const int col = bn + wc + n * 16 + lr;
        const float v = acc[m][n][j];
        if constexpr (BF16_OUT) {
          ((unsigned short*)Cout)[(size_t)row * ldc + col] = f2bf(v);
        } else {
          ((float*)Cout)[(size_t)row * ldc + col] = v + bias[col];
        }
      }
}

// ---------------------------------------------------------------------------
// QKV GEMM with split epilogue: Q -> (B,S,E) head-major, K -> (B,S,E),
// V -> V^T (B,H,64,S). (unchanged, known-good)
// ---------------------------------------------------------------------------
__global__ __launch_bounds__(256) void gemm_qkv(
    const unsigned short* __restrict__ A, const unsigned short* __restrict__ Bt,
    unsigned short* __restrict__ q_bf, unsigned short* __restrict__ k_bf,
    unsigned short* __restrict__ vt_bf, int K) {
  __shared__ alignas(16) unsigned short lds_a[128 * 64];
  __shared__ alignas(16) unsigned short lds_b[128 * 64];
  const int t  = threadIdx.x;
  const int w  = t >> 6, l = t & 63, g = l >> 4, lr = l & 15;
  const int bm = blockIdx.y * 128, bn = blockIdx.x * 128;
  const int wr = (w >> 1) * 64,  wc = (w & 1) * 64;

  f32x4 acc[4][4] = {};

  for (int k0 = 0; k0 < K; k0 += 64) {
    __syncthreads();
#pragma unroll
    for (int i = 0; i < 4; i++) {
      const int pass = w * 4 + i;
      const int r = pass * 8 + (l >> 3);
      const int c = (l & 7) ^ (r & 7);
      gload16(lds_a + pass * 512, A + (size_t)(bm + r) * K + k0 + c * 8);
      gload16(lds_b + pass * 512, Bt + (size_t)(bn + r) * K + k0 + c * 8);
    }
    __syncthreads();

    short8 af[4][2], bfr[4][2];
#pragma unroll
    for (int m = 0; m < 4; m++) {
      const int R = wr + m * 16 + lr;
#pragma unroll
      for (int kk = 0; kk < 2; kk++)
        af[m][kk] = *(const short8*)((const char*)lds_a +
            ((R * 128 + kk * 64 + g * 16) ^ ((R & 7) << 4)));
    }
#pragma unroll
    for (int n = 0; n < 4; n++) {
      const int R = wc + n * 16 + lr;
#pragma unroll
      for (int kk = 0; kk < 2; kk++)
        bfr[n][kk] = *(const short8*)((const char*)lds_b +
            ((R * 128 + kk * 64 + g * 16) ^ ((R & 7) << 4)));
    }
#pragma unroll
    for (int m = 0; m < 4; m++)
#pragma unroll
      for (int n = 0; n < 4; n++) {
        acc[m][n] = __builtin_amdgcn_mfma_f32_16x16x32_bf16(
            af[m][0], bfr[n][0], acc[m][n], 0, 0, 0);
        acc[m][n] = __builtin_amdgcn_mfma_f32_16x16x32_bf16(
            af[m][1], bfr[n][1], acc[m][n], 0, 0, 0);
      }
  }

  const int b = bm >> 11;  // 128-row tiles never cross the S=2048 boundary
#pragma unroll
  for (int n = 0; n < 4; n++) {
    const int col0  = bn + wc + n * 16;       // fragment class is uniform
    const int hcls  = col0 / 192;
    const int cls   = (col0 % 192) / 64;      // 0=Q, 1=K, 2=V
    const int cbase = col0 & 63;
    if (cls == 2) {
      const int d  = cbase + lr;
      const int sl = (bm & 2047) + wr + g * 4;  // + m*16 below
#pragma unroll
      for (int m = 0; m < 4; m++) {
        us16x4 pk;
#pragma unroll
        for (int j = 0; j < 4; j++) pk[j] = f2bf(acc[m][n][j]);
        *(us16x4*)(vt_bf +
            ((size_t)((b * H_ + hcls) * 64 + d) * S_ + sl + m * 16)) = pk;
      }
    } else {
      unsigned short* dst = (cls == 0) ? q_bf : k_bf;
      const int col = hcls * 64 + cbase + lr;
#pragma unroll
      for (int m = 0; m < 4; m++)
#pragma unroll
        for (int j = 0; j < 4; j++) {
          const int row = bm + wr + m * 16 + g * 4 + j;
          dst[(size_t)row * E_ + col] = f2bf(acc[m][n][j]);
        }
    }
  }
}

// ---------------------------------------------------------------------------
// Causal flash attention — BARRIER-FREE, L2-direct K/V.
// K/V per head (256KB each) is L2-resident (all 16 q-blocks of a head land on
// the same XCD: blocks spaced 32 apart, 32 % 8 == 0). So: no K/V LDS staging,
// no __syncthreads at all. Each wave reads K/V fragments straight from global
// (same indexing as before, no swizzle), with register prefetch: kf(t+1)
// issued under softmax+PV, vf(t) issued under softmax. Only LDS use is the
// per-wave P round-trip (lgkmcnt(0) only, wave-local).
// Swapped-operand S^T / O^T layout, lane-local softmax, T13 defer-rescale.
// ---------------------------------------------------------------------------
__global__ __launch_bounds__(256, 2) void attn_fwd(
    const unsigned short* __restrict__ q_bf,
    const unsigned short* __restrict__ k_bf,
    const unsigned short* __restrict__ vt_bf,
    unsigned short* __restrict__ attn_out) {
  __shared__ alignas(16) unsigned short lds_p[4][32 * 64];  // 16 KB per-wave P

  const int t = threadIdx.x;
  const int w = t >> 6, l = t & 63, g = (l >> 4) & 3, lr = l & 15;
  const int bid = blockIdx.x;
  const int bh = bid & 31, b = bh >> 4, h = bh & 15;
  const int rr = bid >> 5;                       // 0..15
  const int bx = (rr < 8) ? rr : 23 - rr;        // pair light+heavy per CU
  const int q0 = bx * 128;
  const int qw = q0 + w * 32;
  const unsigned short* qbase = q_bf + (size_t)b * S_ * E_ + h * HD_;
  const unsigned short* kbase = k_bf + (size_t)b * S_ * E_ + h * HD_;
  const unsigned short* vbase = vt_bf + (size_t)(b * H_ + h) * 64 * S_;

  // Q fragments (B-side): lane (g,lr): Q[qw+m*16+lr][g*8 + kk*32 + 0..7]
  short8 qf[2][2];
#pragma unroll
  for (int m = 0; m < 2; m++) {
    const unsigned short* qp = qbase + (size_t)(qw + m * 16 + lr) * E_ + g * 8;
    qf[m][0] = *(const short8*)qp;
    qf[m][1] = *(const short8*)(qp + 32);
  }

  // O^T accumulator: o[m][dt][j] = O[q=qw+m*16+lr][d=dt*16+g*4+j]
  f32x4 o[2][4] = {};
  float m_r[2] = {-3.0e38f, -3.0e38f};
  float l_r[2] = {0.f, 0.f};
  const float SCALE2 = 0.18033688011112042f;  // 0.125 * log2(e)

  const int numt = (qw >> 6) + 1;  // per-wave tile count (64-wide kv tiles)

  // prologue: K fragments for tile 0 (A-side: K[kv=n*16+lr][g*8 + kk*32])
  short8 kf[4][2];
#pragma unroll
  for (int n = 0; n < 4; n++) {
    const unsigned short* kp = kbase + (size_t)(n * 16 + lr) * E_ + g * 8;
    kf[n][0] = *(const short8*)kp;
    kf[n][1] = *(const short8*)(kp + 32);
  }

  for (int kt = 0; kt < numt; kt++) {
    const int k0 = kt * 64;

    // ---- S^T[64 kv][32 q] = K·Q^T from kf regs ----
    f32x4 st[2][4];
    __builtin_amdgcn_s_setprio(1);
#pragma unroll
    for (int n = 0; n < 4; n++)
#pragma unroll
      for (int m = 0; m < 2; m++) {
        f32x4 z = {};
        z = __builtin_amdgcn_mfma_f32_16x16x32_bf16(kf[n][0], qf[m][0], z, 0, 0, 0);
        z = __builtin_amdgcn_mfma_f32_16x16x32_bf16(kf[n][1], qf[m][1], z, 0, 0, 0);
        st[m][n] = z;
      }
    __builtin_amdgcn_s_setprio(0);

    // ---- issue V^T(t) fragment loads (consumed after softmax) ----
    // A-side: V^T[d=dt*16+lr][kv = k0 + g*8 + kk*32 + 0..7]
    short8 vf[4][2];
#pragma unroll
    for (int dt = 0; dt < 4; dt++) {
      const unsigned short* vp = vbase + (size_t)(dt * 16 + lr) * S_ + k0 + g * 8;
      vf[dt][0] = *(const short8*)vp;
      vf[dt][1] = *(const short8*)(vp + 32);
    }
    // ---- prefetch K fragments for tile t+1 (consumed next iteration) ----
    if (kt + 1 < numt) {
#pragma unroll
      for (int n = 0; n < 4; n++) {
        const unsigned short* kp =
            kbase + (size_t)(k0 + 64 + n * 16 + lr) * E_ + g * 8;
        kf[n][0] = *(const short8*)kp;
        kf[n][1] = *(const short8*)(kp + 32);
      }
    }

    const bool diag = (k0 + 63 > qw);

    // ---- lane-local softmax (q = qw+m*16+lr) + packed P writes ----
#pragma unroll
    for (int m = 0; m < 2; m++) {
      const int qrow = qw + m * 16 + lr;
      if (diag) {
#pragma unroll
        for (int n = 0; n < 4; n++)
#pragma unroll
          for (int j = 0; j < 4; j++)
            if ((k0 + n * 16 + g * 4 + j) > qrow) st[m][n][j] = -3.0e38f;
      }
      // tree max (depth ~4)
      float mxn[4];
#pragma unroll
      for (int n = 0; n < 4; n++)
        mxn[n] = fmaxf(fmaxf(st[m][n][0], st[m][n][1]),
                       fmaxf(st[m][n][2], st[m][n][3]));
      float mx = fmaxf(fmaxf(mxn[0], mxn[1]), fmaxf(mxn[2], mxn[3]));
      mx = fmaxf(mx, __shfl_xor(mx, 16, 64));
      mx = fmaxf(mx, __shfl_xor(mx, 32, 64));
      const float pm = mx * SCALE2;
      // T13 defer-rescale: only rescale when the tile max grows past THR=8
      if (!__all(pm <= m_r[m] + 8.0f)) {
        const float mn = fmaxf(m_r[m], pm);
        const float c  = exp2f(m_r[m] - mn);
        m_r[m] = mn;
        l_r[m] *= c;
#pragma unroll
        for (int dt = 0; dt < 4; dt++) o[m][dt] *= c;
      }
      float p[4][4], sn[4];
#pragma unroll
      for (int n = 0; n < 4; n++) {
#pragma unroll
        for (int j = 0; j < 4; j++)
          p[n][j] = exp2f(fmaf(st[m][n][j], SCALE2, -m_r[m]));
        sn[n] = (p[n][0] + p[n][1]) + (p[n][2] + p[n][3]);
      }
      float sum = (sn[0] + sn[1]) + (sn[2] + sn[3]);
      sum += __shfl_xor(sum, 16, 64);
      sum += __shfl_xor(sum, 32, 64);
      l_r[m] += sum;
      // P[q][kv] -> per-wave LDS: pack j-pairs, ds_write_b64 per n
      char* pb = (char*)lds_p[w];
      const int rowb = (m * 16 + lr) * 128;
      const int sw   = (lr & 7) << 4;
#pragma unroll
      for (int n = 0; n < 4; n++) {
        unsigned w0, w1;
        __asm__("v_cvt_pk_bf16_f32 %0, %1, %2"
                : "=v"(w0) : "v"(p[n][0]), "v"(p[n][1]));
        __asm__("v_cvt_pk_bf16_f32 %0, %1, %2"
                : "=v"(w1) : "v"(p[n][2]), "v"(p[n][3]));
        uint2 val; val.x = w0; val.y = w1;
        *(uint2*)(pb + ((rowb + n * 32 + g * 8) ^ sw)) = val;
      }
    }
    // per-wave LDS round-trip: wait only for this wave's ds_writes
    __asm__ volatile("s_waitcnt lgkmcnt(0)" ::: "memory");

    // ---- PV: O^T += V^T(64d x 64kv) · P^T(64kv x 32q) ----
    short8 pf[2][2];
#pragma unroll
    for (int m = 0; m < 2; m++) {
      const int rowb = (m * 16 + lr) * 128;
      const int sw   = (lr & 7) << 4;
      pf[m][0] = *(const short8*)((const char*)lds_p[w] + ((rowb + g * 16) ^ sw));
      pf[m][1] = *(const short8*)((const char*)lds_p[w] + ((rowb + 64 + g * 16) ^ sw));
    }
    __builtin_amdgcn_s_setprio(1);
#pragma unroll
    for (int dt = 0; dt < 4; dt++)
#pragma unroll
      for (int m = 0; m < 2; m++) {
        o[m][dt] = __builtin_amdgcn_mfma_f32_16x16x32_bf16(
            vf[dt][0], pf[m][0], o[m][dt], 0, 0, 0);
        o[m][dt] = __builtin_amdgcn_mfma_f32_16x16x32_bf16(
            vf[dt][1], pf[m][1], o[m][dt], 0, 0, 0);
      }
    __builtin_amdgcn_s_setprio(0);
  }

  // ---- epilogue: O = O^T scaled by lane-local 1/l, 8B stores ----
  unsigned short* outp = attn_out + (size_t)b * S_ * E_ + h * HD_;
#pragma unroll
  for (int m = 0; m < 2; m++) {
    const float inv = 1.0f / l_r[m];
    const int qrow = qw + m * 16 + lr;
#pragma unroll
    for (int dt = 0; dt < 4; dt++) {
      us16x4 w4;
#pragma unroll
      for (int j = 0; j < 4; j++) w4[j] = f2bf(o[m][dt][j] * inv);
      *(us16x4*)(outp + (size_t)qrow * E_ + dt * 16 + g * 4) = w4;
    }
  }
}

// ---------------------------------------------------------------------------
extern "C" void kernel_launch(void* const* d_in, const int* in_sizes, int n_in,
                              void* d_out, int out_size, void* d_ws, size_t ws_size,
                              hipStream_t stream) {
  (void)in_sizes; (void)n_in; (void)out_size; (void)ws_size;
  const float* x      = (const float*)d_in[0];
  const float* w_qkv  = (const float*)d_in[1];
  const float* w_proj = (const float*)d_in[2];
  const float* b_proj = (const float*)d_in[3];
  float* out = (float*)d_out;

  // workspace layout (all bf16):
  unsigned short* x_bf     = (unsigned short*)d_ws;                 // 4096x1024
  unsigned short* wqkv_bf  = x_bf    + (size_t)M_ * E_;             // 3072x1024
  unsigned short* wproj_bf = wqkv_bf + (size_t)QKVN * E_;           // 1024x1024
  unsigned short* q_bf     = wproj_bf + (size_t)E_ * E_;            // 4096x1024
  unsigned short* k_bf     = q_bf    + (size_t)M_ * E_;             // 4096x1024
  unsigned short* vt_bf    = k_bf    + (size_t)M_ * E_;             // (B,H,64,S)
  unsigned short* attn_bf  = vt_bf   + (size_t)M_ * E_;             // 4096x1024

  int n4;
  n4 = M_ * E_ / 4;
  cvt_f32_to_bf16<<<(n4 + 255) / 256, 256, 0, stream>>>(x, x_bf, n4);
  n4 = QKVN * E_ / 4;
  cvt_f32_to_bf16<<<(n4 + 255) / 256, 256, 0, stream>>>(w_qkv, wqkv_bf, n4);
  n4 = E_ * E_ / 4;
  cvt_f32_to_bf16<<<(n4 + 255) / 256, 256, 0, stream>>>(w_proj, wproj_bf, n4);

  // QKV projection with split Q/K/V^T epilogue
  gemm_qkv<<<dim3(QKVN / 128, M_ / 128), 256, 0, stream>>>(
      x_bf, wqkv_bf, q_bf, k_bf, vt_bf, E_);

  // causal attention: 512 blocks, work-paired, barrier-free
  attn_fwd<<<dim3(512), 256, 0, stream>>>(q_bf, k_bf, vt_bf, attn_bf);

  // output projection + bias: BN=64 tile -> 512 blocks (2/CU)
  gemm_bt<0, 64><<<dim3(E_ / 64, M_ / 128), 256, 0, stream>>>(
      attn_bf, wproj_bf, (void*)out, b_proj, M_, E_, E_, E_);
}